// Round 1
// baseline (3198.273 us; speedup 1.0000x reference)
//
#include <hip/hip_runtime.h>

// ComplexLinearAndLeakyReLU fused kernel — round 1: correct fp32 baseline.
// B=8, C=2048, E=256, F=256. One workgroup = one b, CT=4 consecutive c's.

constexpr float EPSf  = 1e-6f;
constexpr float SLOPE = 0.2f;
constexpr int Bdim = 8, Cdim = 2048, Edim = 256, Fdim = 256;
constexpr int CT = 4;

__device__ __forceinline__ float comp(const float4& v, int k) {
    return k == 0 ? v.x : k == 1 ? v.y : k == 2 ? v.z : v.w;
}

__global__ __launch_bounds__(256)
void fused_cl_lrelu(const float* __restrict__ Xp, const float* __restrict__ Jp,
                    const float* __restrict__ Ap, const float* __restrict__ Bp,
                    const float* __restrict__ Cp, const float* __restrict__ Wp,
                    float* __restrict__ outp)
{
    // abc staging: per (c,e) three float4s: {a0,a1,a2,b0},{b1,b2,c0,c1},{c2,-,-,-}
    __shared__ float4 sabc[CT * Edim * 3];      // 48 KiB (reused as out-stage)
    __shared__ float  ylds[CT * 3][Fdim];       // 12 KiB  [c*3+i][g]

    const int t   = threadIdx.x;
    const int blk = blockIdx.x;
    const int s0  = blk * CT;          // flattened (b,c) base
    const int b   = s0 / Cdim;
    const int c0  = s0 % Cdim;

    // ---------------- phase 1: basis + abc -> LDS ----------------
    #pragma unroll
    for (int r = 0; r < CT; ++r) {
        const int cc = r;          // c within tile
        const int e  = t;          // 256 threads cover e
        const int idx = ((b * Cdim + c0 + cc) * Edim + e) * 3;
        const float Jx = Jp[idx + 0], Jy = Jp[idx + 1], Jz = Jp[idx + 2];
        const float Xx = Xp[idx + 0], Xy = Xp[idx + 1], Xz = Xp[idx + 2];

        const float jn  = sqrtf(Jx*Jx + Jy*Jy + Jz*Jz) + EPSf;
        const float nJx = Jx / jn, nJy = Jy / jn, nJz = Jz / jn;
        const float Uz  = -(nJx*nJx + nJy*nJy) / (nJz + EPSf);
        const float un  = sqrtf(nJx*nJx + nJy*nJy + Uz*Uz) + EPSf;
        const float nUx = nJx / un, nUy = nJy / un, nUz = Uz / un;
        const float nVx = nUy*nJz - nUz*nJy;
        const float nVy = nUz*nJx - nUx*nJz;
        const float nVz = nUx*nJy - nUy*nJx;

        // rtx_i = nU_i*X0 + nV_i*X1 + nJ_i*X2
        const float r0 = nUx*Xx + nVx*Xy + nJx*Xz;
        const float r1 = nUy*Xx + nVy*Xy + nJy*Xz;
        const float r2 = nUz*Xx + nVz*Xy + nJz*Xz;

        // a_k = Rk0*r0 + Rk1*r1 ; b_k = Rk1*r0 - Rk0*r1 ; c_k = Rk2*r2
        const float a0 = nUx*r0 + nUy*r1;
        const float a1 = nVx*r0 + nVy*r1;
        const float a2 = nJx*r0 + nJy*r1;
        const float b0 = nUy*r0 - nUx*r1;
        const float b1 = nVy*r0 - nVx*r1;
        const float b2 = nJy*r0 - nJx*r1;
        const float cA = nUz*r2;
        const float cB = nVz*r2;
        const float cC = nJz*r2;

        const int base = (cc * Edim + e) * 3;
        sabc[base + 0] = make_float4(a0, a1, a2, b0);
        sabc[base + 1] = make_float4(b1, b2, cA, cB);
        sabc[base + 2] = make_float4(cC, 0.f, 0.f, 0.f);
    }
    __syncthreads();

    // ---------------- phase 2: Y[f,c,i] = A*a + Bw*b + Cw*c over e ----------------
    const int fl = t & 63;   // f lane; thread owns f in {64q+fl}
    const int cg = t >> 6;   // this thread's c within the tile (wave-uniform)

    float Y[4][3];
    #pragma unroll
    for (int q = 0; q < 4; ++q)
        Y[q][0] = Y[q][1] = Y[q][2] = 0.f;

    const float4* A4 = reinterpret_cast<const float4*>(Ap);
    const float4* B4 = reinterpret_cast<const float4*>(Bp);
    const float4* C4 = reinterpret_cast<const float4*>(Cp);

    for (int e4 = 0; e4 < Edim / 4; ++e4) {
        float4 wa[4], wb[4], wc[4];
        #pragma unroll
        for (int q = 0; q < 4; ++q) {
            const int f = q * 64 + fl;
            wa[q] = A4[f * (Edim / 4) + e4];
            wb[q] = B4[f * (Edim / 4) + e4];
            wc[q] = C4[f * (Edim / 4) + e4];
        }
        #pragma unroll
        for (int k = 0; k < 4; ++k) {
            const int e = e4 * 4 + k;
            const float4 p0 = sabc[(cg * Edim + e) * 3 + 0];  // broadcast reads
            const float4 p1 = sabc[(cg * Edim + e) * 3 + 1];
            const float4 p2 = sabc[(cg * Edim + e) * 3 + 2];
            const float a0 = p0.x, a1 = p0.y, a2 = p0.z, b0 = p0.w;
            const float b1 = p1.x, b2 = p1.y, cA = p1.z, cB = p1.w;
            const float cC = p2.x;
            #pragma unroll
            for (int q = 0; q < 4; ++q) {
                const float Af = comp(wa[q], k);
                const float Bf = comp(wb[q], k);
                const float Cf = comp(wc[q], k);
                Y[q][0] += Af * a0 + Bf * b0 + Cf * cA;
                Y[q][1] += Af * a1 + Bf * b1 + Cf * cB;
                Y[q][2] += Af * a2 + Bf * b2 + Cf * cC;
            }
        }
    }

    // stage Y for the W-contraction
    #pragma unroll
    for (int q = 0; q < 4; ++q) {
        const int f = q * 64 + fl;
        ylds[cg * 3 + 0][f] = Y[q][0];
        ylds[cg * 3 + 1][f] = Y[q][1];
        ylds[cg * 3 + 2][f] = Y[q][2];
    }
    __syncthreads();

    // ---------------- phase 3: d[f,i] = sum_g W[f,g] * Y[g,i] ----------------
    float D[4][3];
    #pragma unroll
    for (int q = 0; q < 4; ++q)
        D[q][0] = D[q][1] = D[q][2] = 0.f;

    const float4* W4 = reinterpret_cast<const float4*>(Wp);
    for (int g4 = 0; g4 < Fdim / 4; ++g4) {
        float4 ww[4];
        #pragma unroll
        for (int q = 0; q < 4; ++q) {
            const int f = q * 64 + fl;
            ww[q] = W4[f * (Fdim / 4) + g4];
        }
        const float4 y0 = *reinterpret_cast<const float4*>(&ylds[cg * 3 + 0][g4 * 4]);
        const float4 y1 = *reinterpret_cast<const float4*>(&ylds[cg * 3 + 1][g4 * 4]);
        const float4 y2 = *reinterpret_cast<const float4*>(&ylds[cg * 3 + 2][g4 * 4]);
        #pragma unroll
        for (int k = 0; k < 4; ++k) {
            const float yk0 = comp(y0, k), yk1 = comp(y1, k), yk2 = comp(y2, k);
            #pragma unroll
            for (int q = 0; q < 4; ++q) {
                const float Wf = comp(ww[q], k);
                D[q][0] += Wf * yk0;
                D[q][1] += Wf * yk1;
                D[q][2] += Wf * yk2;
            }
        }
    }

    // ---------------- epilogue: leaky projection, stage to LDS ----------------
    // reuse sabc region as float outl[256][3][4]  (f, i, c)
    float* outl = reinterpret_cast<float*>(sabc);
    #pragma unroll
    for (int q = 0; q < 4; ++q) {
        const int f = q * 64 + fl;
        const float dot = Y[q][0]*D[q][0] + Y[q][1]*D[q][1] + Y[q][2]*D[q][2];
        const float dns = D[q][0]*D[q][0] + D[q][1]*D[q][1] + D[q][2]*D[q][2] + EPSf;
        const float s   = dot / dns;
        const bool  pos = (dot >= 0.f);
        #pragma unroll
        for (int i = 0; i < 3; ++i) {
            const float x = Y[q][i];
            const float d = D[q][i];
            const float corr = x - s * d;
            const float val  = SLOPE * x + (1.f - SLOPE) * (pos ? x : corr);
            outl[(f * 3 + i) * 4 + cg] = val;
        }
    }
    __syncthreads();

    // ---------------- coalesced-ish float4 output writes ----------------
    // out[b][f][i][c] ; thread t handles f=t, i=0..2, c0..c0+3 as one float4
    const float4* o4 = reinterpret_cast<const float4*>(outl);
    float4* O4 = reinterpret_cast<float4*>(outp);
    const int c4 = c0 >> 2;
    #pragma unroll
    for (int i = 0; i < 3; ++i) {
        O4[((b * Fdim + t) * 3 + i) * (Cdim / 4) + c4] = o4[t * 3 + i];
    }
}

extern "C" void kernel_launch(void* const* d_in, const int* in_sizes, int n_in,
                              void* d_out, int out_size, void* d_ws, size_t ws_size,
                              hipStream_t stream) {
    const float* X  = (const float*)d_in[0];
    const float* J  = (const float*)d_in[1];
    const float* A  = (const float*)d_in[2];
    const float* Bw = (const float*)d_in[3];
    const float* Cw = (const float*)d_in[4];
    const float* W  = (const float*)d_in[5];
    float* out = (float*)d_out;

    dim3 grid(Bdim * Cdim / CT);
    dim3 block(256);
    hipLaunchKernelGGL(fused_cl_lrelu, grid, block, 0, stream, X, J, A, Bw, Cw, W, out);
}

// Round 3
// 76.508 us; speedup vs baseline: 41.8032x; 41.8032x over previous
//
#include <hip/hip_runtime.h>

// ComplexLinearAndLeakyReLU — round 3: fp16 MFMA + bit-exact (np-matching) basis.
// B=8, C=2048, E=256, F=256. Block = 16 sites (one b, 16 consecutive c).
// GEMM1: Y[f,n] = sum_k M[f,k] Z[k,n], M=[A|Bw|Cw] (256x768), n = i*16+s (48 cols)
// GEMM2: D[f,n] = sum_g W[f,g] Yf16[g,n]
// Epilogue per (f,s): dot/dns over i (i = n-tile index, same lane) -> leaky projection.

constexpr float EPSf  = 1e-6f;
constexpr int Bdim = 8, Cdim = 2048, Edim = 256, Fdim = 256;
constexpr int NT  = 16;          // sites per block
constexpr int KC1 = 24;          // GEMM1 K chunks of 32 (K=768)
constexpr int KC2 = 8;           // GEMM2 K chunks of 32 (K=256)
constexpr int ZLD = 776;         // Zt row stride in halves (768 + 8 pad)
constexpr int YLD = 264;         // Yt row stride in halves (256 + 8 pad)
constexpr int M_ROWS = KC1 * 16 * 64;   // 24576 fragment rows (M weights)
constexpr int W_ROWS = KC2 * 16 * 64;   // 8192 fragment rows (W weights)

typedef __attribute__((ext_vector_type(8))) _Float16 half8;
typedef __attribute__((ext_vector_type(4))) _Float16 half4;
typedef __attribute__((ext_vector_type(4))) float    f32x4;

// ---- basis + abc, bit-exact vs numpy (no FMA contraction, IEEE div/sqrt) ----
__device__ __forceinline__ void basis_abc(float Xx, float Xy, float Xz,
                                          float Jx, float Jy, float Jz,
                                          float* a, float* bb, float* cc)
{
#pragma clang fp contract(off)
    const float jn  = sqrtf((Jx*Jx + Jy*Jy) + Jz*Jz) + EPSf;
    const float nJx = Jx / jn, nJy = Jy / jn, nJz = Jz / jn;
    const float Uz  = (-((nJx*nJx) + (nJy*nJy))) / (nJz + EPSf);
    const float un  = sqrtf(((nJx*nJx) + (nJy*nJy)) + Uz*Uz) + EPSf;
    const float nUx = nJx / un, nUy = nJy / un, nUz = Uz / un;
    // nV = cross(nU, nJ)
    const float nVx = nUy*nJz - nUz*nJy;
    const float nVy = nUz*nJx - nUx*nJz;
    const float nVz = nUx*nJy - nUy*nJx;
    // rtx_i = R[0,i]X0 + R[1,i]X1 + R[2,i]X2   (R rows: nU,nV,nJ)
    const float r0 = (nUx*Xx + nVx*Xy) + nJx*Xz;
    const float r1 = (nUy*Xx + nVy*Xy) + nJy*Xz;
    const float r2 = (nUz*Xx + nVz*Xy) + nJz*Xz;
    // a_k = R[k,0]r0 + R[k,1]r1 ; b_k = R[k,1]r0 - R[k,0]r1 ; c_k = R[k,2]r2
    a[0]  = nUx*r0 + nUy*r1;   a[1]  = nVx*r0 + nVy*r1;   a[2]  = nJx*r0 + nJy*r1;
    bb[0] = nUy*r0 - nUx*r1;   bb[1] = nVy*r0 - nVx*r1;   bb[2] = nJy*r0 - nJx*r1;
    cc[0] = nUz*r2;            cc[1] = nVz*r2;            cc[2] = nJz*r2;
}

// ---------------- weight prep: fp32 -> fp16 in MFMA A-fragment order ----------------
// buf[(kc*16 + ft)*64 + lane][j] holds M[ft*16 + (lane&15)][kc*32 + (lane>>4)*8 + j]
__global__ __launch_bounds__(256)
void prep_weights_f16(const float* __restrict__ Ap, const float* __restrict__ Bp,
                      const float* __restrict__ Cp, const float* __restrict__ Wp,
                      _Float16* __restrict__ ws)
{
    const int tid = blockIdx.x * 256 + threadIdx.x;          // 0 .. 32767
    const bool isW = tid >= M_ROWS;
    const int row = isW ? tid - M_ROWS : tid;
    const int l   = row & 63;
    const int ft  = (row >> 6) & 15;
    const int kc  = row >> 10;
    const int f   = ft * 16 + (l & 15);
    const int k0  = kc * 32 + ((l >> 4) << 3);

    const float* src;
    int e0;
    if (isW)            { src = Wp; e0 = k0; }
    else if (k0 < 256)  { src = Ap; e0 = k0; }
    else if (k0 < 512)  { src = Bp; e0 = k0 - 256; }
    else                { src = Cp; e0 = k0 - 512; }

    const float* p = src + f * 256 + e0;
    half8 v;
    #pragma unroll
    for (int j = 0; j < 8; ++j) v[j] = (_Float16)p[j];

    _Float16* dst = ws + (isW ? (size_t)M_ROWS * 8 : 0);
    *reinterpret_cast<half8*>(dst + (size_t)row * 8) = v;
}

// ---------------- fused main kernel ----------------
__global__ __launch_bounds__(256, 2)
void fused_mfma_f16(const float* __restrict__ Xp, const float* __restrict__ Jp,
                    const _Float16* __restrict__ wsM, const _Float16* __restrict__ wsW,
                    float* __restrict__ outp)
{
    // Zt[48][ZLD] fp16 for GEMM1 B-operand; after GEMM1, aliased as Yt[48][YLD].
    __shared__ __align__(16) _Float16 lds[48 * ZLD];   // 74,496 B -> 2 blocks/CU

    const int t  = threadIdx.x;
    const int s0 = blockIdx.x * NT;
    const int b  = s0 >> 11;          // / Cdim
    const int c0 = s0 & (Cdim - 1);

    // ---- phase 1: basis + abc -> Zt (fp16), e-quad per thread ----
    {
        const int equad = t & 63;     // e0 = 4*equad
        const int sq    = t >> 6;     // site group, 4 sites each
        const int e0    = equad * 4;
        #pragma unroll
        for (int ss = 0; ss < 4; ++ss) {
            const int s = sq * 4 + ss;
            const long site = (long)(b * Cdim + c0 + s);
            const float4* X4 = reinterpret_cast<const float4*>(Xp) + site * 192 + equad * 3;
            const float4* J4 = reinterpret_cast<const float4*>(Jp) + site * 192 + equad * 3;
            const float4 xA = X4[0], xB = X4[1], xC = X4[2];
            const float4 jA = J4[0], jB = J4[1], jC = J4[2];
            const float xf[12] = {xA.x,xA.y,xA.z,xA.w, xB.x,xB.y,xB.z,xB.w, xC.x,xC.y,xC.z,xC.w};
            const float jf[12] = {jA.x,jA.y,jA.z,jA.w, jB.x,jB.y,jB.z,jB.w, jC.x,jC.y,jC.z,jC.w};

            half4 za[3], zb[3], zc[3];
            #pragma unroll
            for (int ee = 0; ee < 4; ++ee) {
                float a[3], bb[3], cc[3];
                basis_abc(xf[3*ee], xf[3*ee+1], xf[3*ee+2],
                          jf[3*ee], jf[3*ee+1], jf[3*ee+2], a, bb, cc);
                #pragma unroll
                for (int i = 0; i < 3; ++i) {
                    za[i][ee] = (_Float16)a[i];
                    zb[i][ee] = (_Float16)bb[i];
                    zc[i][ee] = (_Float16)cc[i];
                }
            }
            // Zt[n = i*16+s][k = m*256+e]; m: 0->a(A), 1->b(Bw), 2->c(Cw)
            #pragma unroll
            for (int i = 0; i < 3; ++i) {
                _Float16* rowp = &lds[(i * NT + s) * ZLD];
                *reinterpret_cast<half4*>(rowp +       e0) = za[i];
                *reinterpret_cast<half4*>(rowp + 256 + e0) = zb[i];
                *reinterpret_cast<half4*>(rowp + 512 + e0) = zc[i];
            }
        }
    }
    __syncthreads();

    const int wid = t >> 6;          // wave id: owns f-tiles wid*4 .. wid*4+3
    const int l   = t & 63;
    const int lr  = l & 15;          // within-tile row/col
    const int lk  = (l >> 4) * 8;    // k-offset of this lane's 8 elements

    // ---- phase 2: GEMM1, Yacc[q][nt] over K=768 ----
    f32x4 Yacc[4][3];
    #pragma unroll
    for (int q = 0; q < 4; ++q)
        #pragma unroll
        for (int nt = 0; nt < 3; ++nt)
            Yacc[q][nt] = f32x4{0.f, 0.f, 0.f, 0.f};

    const half8* Mf = reinterpret_cast<const half8*>(wsM);
    for (int kc = 0; kc < KC1; ++kc) {
        half8 af[4];
        #pragma unroll
        for (int q = 0; q < 4; ++q)
            af[q] = Mf[(kc * 16 + wid * 4 + q) * 64 + l];
        half8 zf[3];
        #pragma unroll
        for (int nt = 0; nt < 3; ++nt)
            zf[nt] = *reinterpret_cast<const half8*>(&lds[(nt * NT + lr) * ZLD + kc * 32 + lk]);
        #pragma unroll
        for (int q = 0; q < 4; ++q)
            #pragma unroll
            for (int nt = 0; nt < 3; ++nt)
                Yacc[q][nt] = __builtin_amdgcn_mfma_f32_16x16x32_f16(af[q], zf[nt], Yacc[q][nt], 0, 0, 0);
    }
    __syncthreads();   // all Zt reads done; safe to alias as Yt

    // ---- stage Y as fp16 Yt[col][row] for GEMM2 B-operand ----
    #pragma unroll
    for (int q = 0; q < 4; ++q) {
        const int row = (wid * 4 + q) * 16 + (l >> 4) * 4;   // g index of reg 0
        #pragma unroll
        for (int nt = 0; nt < 3; ++nt) {
            const int col = nt * NT + lr;
            half4 v = { (_Float16)Yacc[q][nt][0], (_Float16)Yacc[q][nt][1],
                        (_Float16)Yacc[q][nt][2], (_Float16)Yacc[q][nt][3] };
            *reinterpret_cast<half4*>(&lds[col * YLD + row]) = v;
        }
    }
    __syncthreads();

    // ---- phase 3: GEMM2, Dacc[q][nt] over K=256 ----
    f32x4 Dacc[4][3];
    #pragma unroll
    for (int q = 0; q < 4; ++q)
        #pragma unroll
        for (int nt = 0; nt < 3; ++nt)
            Dacc[q][nt] = f32x4{0.f, 0.f, 0.f, 0.f};

    const half8* Wf = reinterpret_cast<const half8*>(wsW);
    for (int kc = 0; kc < KC2; ++kc) {
        half8 af[4];
        #pragma unroll
        for (int q = 0; q < 4; ++q)
            af[q] = Wf[(kc * 16 + wid * 4 + q) * 64 + l];
        half8 yf[3];
        #pragma unroll
        for (int nt = 0; nt < 3; ++nt)
            yf[nt] = *reinterpret_cast<const half8*>(&lds[(nt * NT + lr) * YLD + kc * 32 + lk]);
        #pragma unroll
        for (int q = 0; q < 4; ++q)
            #pragma unroll
            for (int nt = 0; nt < 3; ++nt)
                Dacc[q][nt] = __builtin_amdgcn_mfma_f32_16x16x32_f16(af[q], yf[nt], Dacc[q][nt], 0, 0, 0);
    }

    // ---- epilogue: leaky projection (np-exact op order), direct stores ----
    #pragma unroll
    for (int q = 0; q < 4; ++q) {
        const int fbase = (wid * 4 + q) * 16 + (l >> 4) * 4;
        #pragma unroll
        for (int r = 0; r < 4; ++r) {
#pragma clang fp contract(off)
            const float x0 = Yacc[q][0][r], x1 = Yacc[q][1][r], x2 = Yacc[q][2][r];
            const float d0 = Dacc[q][0][r], d1 = Dacc[q][1][r], d2 = Dacc[q][2][r];
            const float dot = (x0*d0 + x1*d1) + x2*d2;
            const float dns = (d0*d0 + d1*d1) + d2*d2;
            const float sc  = dot / (dns + EPSf);
            const bool  pos = (dot >= 0.f);
            const int f = fbase + r;
            const long obase = ((long)(b * Fdim + f) * 3) * Cdim + c0 + lr;
            const float c0v = pos ? x0 : (x0 - sc*d0);
            const float c1v = pos ? x1 : (x1 - sc*d1);
            const float c2v = pos ? x2 : (x2 - sc*d2);
            outp[obase + 0 * Cdim] = 0.2f*x0 + 0.8f*c0v;
            outp[obase + 1 * Cdim] = 0.2f*x1 + 0.8f*c1v;
            outp[obase + 2 * Cdim] = 0.2f*x2 + 0.8f*c2v;
        }
    }
}

// ---------------- fp32 fallback (round-1 kernel, passed) if ws too small ----------------
__device__ __forceinline__ float comp(const float4& v, int k) {
    return k == 0 ? v.x : k == 1 ? v.y : k == 2 ? v.z : v.w;
}

__global__ __launch_bounds__(256)
void fused_cl_lrelu_fp32(const float* __restrict__ Xp, const float* __restrict__ Jp,
                         const float* __restrict__ Ap, const float* __restrict__ Bp,
                         const float* __restrict__ Cp, const float* __restrict__ Wp,
                         float* __restrict__ outp)
{
    __shared__ float4 sabc[4 * Edim * 3];
    __shared__ float  ylds[4 * 3][Fdim];

    const int t   = threadIdx.x;
    const int s0  = blockIdx.x * 4;
    const int b   = s0 / Cdim;
    const int c0  = s0 % Cdim;

    #pragma unroll
    for (int r = 0; r < 4; ++r) {
        const int e  = t;
        const int idx = ((b * Cdim + c0 + r) * Edim + e) * 3;
        float a[3], bb[3], cc[3];
        basis_abc(Xp[idx], Xp[idx+1], Xp[idx+2], Jp[idx], Jp[idx+1], Jp[idx+2], a, bb, cc);
        const int base = (r * Edim + e) * 3;
        sabc[base + 0] = make_float4(a[0], a[1], a[2], bb[0]);
        sabc[base + 1] = make_float4(bb[1], bb[2], cc[0], cc[1]);
        sabc[base + 2] = make_float4(cc[2], 0.f, 0.f, 0.f);
    }
    __syncthreads();

    const int fl = t & 63;
    const int cg = t >> 6;
    float Y[4][3];
    #pragma unroll
    for (int q = 0; q < 4; ++q) Y[q][0] = Y[q][1] = Y[q][2] = 0.f;

    const float4* A4 = reinterpret_cast<const float4*>(Ap);
    const float4* B4 = reinterpret_cast<const float4*>(Bp);
    const float4* C4 = reinterpret_cast<const float4*>(Cp);
    for (int e4 = 0; e4 < Edim / 4; ++e4) {
        float4 wa[4], wb[4], wc[4];
        #pragma unroll
        for (int q = 0; q < 4; ++q) {
            const int f = q * 64 + fl;
            wa[q] = A4[f * (Edim/4) + e4];
            wb[q] = B4[f * (Edim/4) + e4];
            wc[q] = C4[f * (Edim/4) + e4];
        }
        #pragma unroll
        for (int k = 0; k < 4; ++k) {
            const int e = e4 * 4 + k;
            const float4 p0 = sabc[(cg * Edim + e) * 3 + 0];
            const float4 p1 = sabc[(cg * Edim + e) * 3 + 1];
            const float4 p2 = sabc[(cg * Edim + e) * 3 + 2];
            #pragma unroll
            for (int q = 0; q < 4; ++q) {
                const float Af = comp(wa[q], k), Bf = comp(wb[q], k), Cf = comp(wc[q], k);
                Y[q][0] += Af * p0.x + Bf * p0.w + Cf * p1.z;
                Y[q][1] += Af * p0.y + Bf * p1.x + Cf * p1.w;
                Y[q][2] += Af * p0.z + Bf * p1.y + Cf * p2.x;
            }
        }
    }
    #pragma unroll
    for (int q = 0; q < 4; ++q) {
        const int f = q * 64 + fl;
        ylds[cg * 3 + 0][f] = Y[q][0];
        ylds[cg * 3 + 1][f] = Y[q][1];
        ylds[cg * 3 + 2][f] = Y[q][2];
    }
    __syncthreads();

    float D[4][3];
    #pragma unroll
    for (int q = 0; q < 4; ++q) D[q][0] = D[q][1] = D[q][2] = 0.f;
    const float4* W4 = reinterpret_cast<const float4*>(Wp);
    for (int g4 = 0; g4 < Fdim / 4; ++g4) {
        float4 ww[4];
        #pragma unroll
        for (int q = 0; q < 4; ++q) ww[q] = W4[(q * 64 + fl) * (Fdim/4) + g4];
        const float4 y0 = *reinterpret_cast<const float4*>(&ylds[cg * 3 + 0][g4 * 4]);
        const float4 y1 = *reinterpret_cast<const float4*>(&ylds[cg * 3 + 1][g4 * 4]);
        const float4 y2 = *reinterpret_cast<const float4*>(&ylds[cg * 3 + 2][g4 * 4]);
        #pragma unroll
        for (int k = 0; k < 4; ++k) {
            #pragma unroll
            for (int q = 0; q < 4; ++q) {
                const float Wv = comp(ww[q], k);
                D[q][0] += Wv * comp(y0, k);
                D[q][1] += Wv * comp(y1, k);
                D[q][2] += Wv * comp(y2, k);
            }
        }
    }

    float* outl = reinterpret_cast<float*>(sabc);
    #pragma unroll
    for (int q = 0; q < 4; ++q) {
        const int f = q * 64 + fl;
        const float dot = (Y[q][0]*D[q][0] + Y[q][1]*D[q][1]) + Y[q][2]*D[q][2];
        const float dns = (D[q][0]*D[q][0] + D[q][1]*D[q][1]) + D[q][2]*D[q][2];
        const float s   = dot / (dns + EPSf);
        const bool  pos = (dot >= 0.f);
        #pragma unroll
        for (int i = 0; i < 3; ++i) {
            const float x = Y[q][i], d = D[q][i];
            outl[(f * 3 + i) * 4 + cg] = 0.2f*x + 0.8f*(pos ? x : x - s*d);
        }
    }
    __syncthreads();
    const float4* o4 = reinterpret_cast<const float4*>(outl);
    float4* O4 = reinterpret_cast<float4*>(outp);
    const int c4 = c0 >> 2;
    #pragma unroll
    for (int i = 0; i < 3; ++i)
        O4[((b * Fdim + t) * 3 + i) * (Cdim / 4) + c4] = o4[t * 3 + i];
}

extern "C" void kernel_launch(void* const* d_in, const int* in_sizes, int n_in,
                              void* d_out, int out_size, void* d_ws, size_t ws_size,
                              hipStream_t stream) {
    const float* X  = (const float*)d_in[0];
    const float* J  = (const float*)d_in[1];
    const float* A  = (const float*)d_in[2];
    const float* Bw = (const float*)d_in[3];
    const float* Cw = (const float*)d_in[4];
    const float* W  = (const float*)d_in[5];
    float* out = (float*)d_out;

    constexpr size_t WS_NEED = (size_t)(M_ROWS + W_ROWS) * 8 * sizeof(_Float16);  // 512 KiB
    if (ws_size >= WS_NEED) {
        _Float16* wsM = (_Float16*)d_ws;
        _Float16* wsW = wsM + (size_t)M_ROWS * 8;
        prep_weights_f16<<<(M_ROWS + W_ROWS) / 256, 256, 0, stream>>>(A, Bw, Cw, W, wsM);
        fused_mfma_f16<<<Bdim * Cdim / NT, 256, 0, stream>>>(X, J, wsM, wsW, out);
    } else {
        fused_cl_lrelu_fp32<<<Bdim * Cdim / 4, 256, 0, stream>>>(X, J, A, Bw, Cw, W, out);
    }
}

// Round 4
// 59.450 us; speedup vs baseline: 53.7978x; 1.2869x over previous
//
#include <hip/hip_runtime.h>

// ComplexLinearAndLeakyReLU — round 4: fp16 MFMA, 512-thread blocks (8 waves)
// for 16 waves/CU occupancy (was 8). Same validated math as round 3.
// B=8, C=2048, E=256, F=256. Block = 16 sites (one b, 16 consecutive c).
// GEMM1: Y[f,n] = sum_k M[f,k] Z[k,n], M=[A|Bw|Cw] (256x768), n = i*16+s (48 cols)
// GEMM2: D[f,n] = sum_g W[f,g] Yf16[g,n]
// Epilogue per (f,s): dot/dns over i (i = n-tile index, same lane) -> leaky projection.

constexpr float EPSf  = 1e-6f;
constexpr int Bdim = 8, Cdim = 2048, Edim = 256, Fdim = 256;
constexpr int NT  = 16;          // sites per block
constexpr int KC1 = 24;          // GEMM1 K chunks of 32 (K=768)
constexpr int KC2 = 8;           // GEMM2 K chunks of 32 (K=256)
constexpr int ZLD = 776;         // Zt row stride in halves (768 + 8 pad)
constexpr int YLD = 264;         // Yt row stride in halves (256 + 8 pad)
constexpr int M_ROWS = KC1 * 16 * 64;   // 24576 fragment rows (M weights)
constexpr int W_ROWS = KC2 * 16 * 64;   // 8192 fragment rows (W weights)

typedef __attribute__((ext_vector_type(8))) _Float16 half8;
typedef __attribute__((ext_vector_type(4))) _Float16 half4;
typedef __attribute__((ext_vector_type(4))) float    f32x4;

// ---- basis + abc, bit-exact vs numpy (no FMA contraction, IEEE div/sqrt) ----
__device__ __forceinline__ void basis_abc(float Xx, float Xy, float Xz,
                                          float Jx, float Jy, float Jz,
                                          float* a, float* bb, float* cc)
{
#pragma clang fp contract(off)
    const float jn  = sqrtf((Jx*Jx + Jy*Jy) + Jz*Jz) + EPSf;
    const float nJx = Jx / jn, nJy = Jy / jn, nJz = Jz / jn;
    const float Uz  = (-((nJx*nJx) + (nJy*nJy))) / (nJz + EPSf);
    const float un  = sqrtf(((nJx*nJx) + (nJy*nJy)) + Uz*Uz) + EPSf;
    const float nUx = nJx / un, nUy = nJy / un, nUz = Uz / un;
    // nV = cross(nU, nJ)
    const float nVx = nUy*nJz - nUz*nJy;
    const float nVy = nUz*nJx - nUx*nJz;
    const float nVz = nUx*nJy - nUy*nJx;
    // rtx_i = R[0,i]X0 + R[1,i]X1 + R[2,i]X2   (R rows: nU,nV,nJ)
    const float r0 = (nUx*Xx + nVx*Xy) + nJx*Xz;
    const float r1 = (nUy*Xx + nVy*Xy) + nJy*Xz;
    const float r2 = (nUz*Xx + nVz*Xy) + nJz*Xz;
    // a_k = R[k,0]r0 + R[k,1]r1 ; b_k = R[k,1]r0 - R[k,0]r1 ; c_k = R[k,2]r2
    a[0]  = nUx*r0 + nUy*r1;   a[1]  = nVx*r0 + nVy*r1;   a[2]  = nJx*r0 + nJy*r1;
    bb[0] = nUy*r0 - nUx*r1;   bb[1] = nVy*r0 - nVx*r1;   bb[2] = nJy*r0 - nJx*r1;
    cc[0] = nUz*r2;            cc[1] = nVz*r2;            cc[2] = nJz*r2;
}

// ---------------- weight prep: fp32 -> fp16 in MFMA A-fragment order ----------------
// buf[(kc*16 + ft)*64 + lane][j] holds M[ft*16 + (lane&15)][kc*32 + (lane>>4)*8 + j]
__global__ __launch_bounds__(256)
void prep_weights_f16(const float* __restrict__ Ap, const float* __restrict__ Bp,
                      const float* __restrict__ Cp, const float* __restrict__ Wp,
                      _Float16* __restrict__ ws)
{
    const int tid = blockIdx.x * 256 + threadIdx.x;          // 0 .. 32767
    const bool isW = tid >= M_ROWS;
    const int row = isW ? tid - M_ROWS : tid;
    const int l   = row & 63;
    const int ft  = (row >> 6) & 15;
    const int kc  = row >> 10;
    const int f   = ft * 16 + (l & 15);
    const int k0  = kc * 32 + ((l >> 4) << 3);

    const float* src;
    int e0;
    if (isW)            { src = Wp; e0 = k0; }
    else if (k0 < 256)  { src = Ap; e0 = k0; }
    else if (k0 < 512)  { src = Bp; e0 = k0 - 256; }
    else                { src = Cp; e0 = k0 - 512; }

    const float* p = src + f * 256 + e0;
    half8 v;
    #pragma unroll
    for (int j = 0; j < 8; ++j) v[j] = (_Float16)p[j];

    _Float16* dst = ws + (isW ? (size_t)M_ROWS * 8 : 0);
    *reinterpret_cast<half8*>(dst + (size_t)row * 8) = v;
}

// ---------------- fused main kernel: 512 threads = 8 waves ----------------
__global__ __launch_bounds__(512, 4)
void fused_mfma_f16(const float* __restrict__ Xp, const float* __restrict__ Jp,
                    const _Float16* __restrict__ wsM, const _Float16* __restrict__ wsW,
                    float* __restrict__ outp)
{
    // Zt[48][ZLD] fp16 for GEMM1 B-operand; after GEMM1, aliased as Yt[48][YLD].
    __shared__ __align__(16) _Float16 lds[48 * ZLD];   // 74,496 B -> 2 blocks/CU

    const int t  = threadIdx.x;
    const int s0 = blockIdx.x * NT;
    const int b  = s0 >> 11;          // / Cdim
    const int c0 = s0 & (Cdim - 1);

    // ---- phase 1: basis + abc -> Zt (fp16), e-quad per thread, 2 sites each ----
    {
        const int equad = t & 63;     // e0 = 4*equad
        const int sq    = t >> 6;     // 0..7, each handles 2 sites
        const int e0    = equad * 4;
        #pragma unroll
        for (int ss = 0; ss < 2; ++ss) {
            const int s = sq * 2 + ss;
            const long site = (long)(b * Cdim + c0 + s);
            const float4* X4 = reinterpret_cast<const float4*>(Xp) + site * 192 + equad * 3;
            const float4* J4 = reinterpret_cast<const float4*>(Jp) + site * 192 + equad * 3;
            const float4 xA = X4[0], xB = X4[1], xC = X4[2];
            const float4 jA = J4[0], jB = J4[1], jC = J4[2];
            const float xf[12] = {xA.x,xA.y,xA.z,xA.w, xB.x,xB.y,xB.z,xB.w, xC.x,xC.y,xC.z,xC.w};
            const float jf[12] = {jA.x,jA.y,jA.z,jA.w, jB.x,jB.y,jB.z,jB.w, jC.x,jC.y,jC.z,jC.w};

            half4 za[3], zb[3], zc[3];
            #pragma unroll
            for (int ee = 0; ee < 4; ++ee) {
                float a[3], bb[3], cc[3];
                basis_abc(xf[3*ee], xf[3*ee+1], xf[3*ee+2],
                          jf[3*ee], jf[3*ee+1], jf[3*ee+2], a, bb, cc);
                #pragma unroll
                for (int i = 0; i < 3; ++i) {
                    za[i][ee] = (_Float16)a[i];
                    zb[i][ee] = (_Float16)bb[i];
                    zc[i][ee] = (_Float16)cc[i];
                }
            }
            // Zt[n = i*16+s][k = m*256+e]; m: 0->a(A), 1->b(Bw), 2->c(Cw)
            #pragma unroll
            for (int i = 0; i < 3; ++i) {
                _Float16* rowp = &lds[(i * NT + s) * ZLD];
                *reinterpret_cast<half4*>(rowp +       e0) = za[i];
                *reinterpret_cast<half4*>(rowp + 256 + e0) = zb[i];
                *reinterpret_cast<half4*>(rowp + 512 + e0) = zc[i];
            }
        }
    }
    __syncthreads();

    const int wid = t >> 6;          // wave id 0..7: owns f-tiles wid*2, wid*2+1
    const int l   = t & 63;
    const int lr  = l & 15;          // within-tile row/col
    const int lk  = (l >> 4) * 8;    // k-offset of this lane's 8 elements

    // ---- phase 2: GEMM1, Yacc[q][nt] over K=768 ----
    f32x4 Yacc[2][3];
    #pragma unroll
    for (int q = 0; q < 2; ++q)
        #pragma unroll
        for (int nt = 0; nt < 3; ++nt)
            Yacc[q][nt] = f32x4{0.f, 0.f, 0.f, 0.f};

    const half8* Mf = reinterpret_cast<const half8*>(wsM);
    for (int kc = 0; kc < KC1; ++kc) {
        half8 af[2];
        #pragma unroll
        for (int q = 0; q < 2; ++q)
            af[q] = Mf[(kc * 16 + wid * 2 + q) * 64 + l];
        half8 zf[3];
        #pragma unroll
        for (int nt = 0; nt < 3; ++nt)
            zf[nt] = *reinterpret_cast<const half8*>(&lds[(nt * NT + lr) * ZLD + kc * 32 + lk]);
        #pragma unroll
        for (int q = 0; q < 2; ++q)
            #pragma unroll
            for (int nt = 0; nt < 3; ++nt)
                Yacc[q][nt] = __builtin_amdgcn_mfma_f32_16x16x32_f16(af[q], zf[nt], Yacc[q][nt], 0, 0, 0);
    }
    __syncthreads();   // all Zt reads done; safe to alias as Yt

    // ---- stage Y as fp16 Yt[col][row] for GEMM2 B-operand ----
    #pragma unroll
    for (int q = 0; q < 2; ++q) {
        const int row = (wid * 2 + q) * 16 + (l >> 4) * 4;   // g index of reg 0
        #pragma unroll
        for (int nt = 0; nt < 3; ++nt) {
            const int col = nt * NT + lr;
            half4 v = { (_Float16)Yacc[q][nt][0], (_Float16)Yacc[q][nt][1],
                        (_Float16)Yacc[q][nt][2], (_Float16)Yacc[q][nt][3] };
            *reinterpret_cast<half4*>(&lds[col * YLD + row]) = v;
        }
    }
    __syncthreads();

    // ---- phase 3: GEMM2, Dacc[q][nt] over K=256 ----
    f32x4 Dacc[2][3];
    #pragma unroll
    for (int q = 0; q < 2; ++q)
        #pragma unroll
        for (int nt = 0; nt < 3; ++nt)
            Dacc[q][nt] = f32x4{0.f, 0.f, 0.f, 0.f};

    const half8* Wf = reinterpret_cast<const half8*>(wsW);
    for (int kc = 0; kc < KC2; ++kc) {
        half8 af[2];
        #pragma unroll
        for (int q = 0; q < 2; ++q)
            af[q] = Wf[(kc * 16 + wid * 2 + q) * 64 + l];
        half8 yf[3];
        #pragma unroll
        for (int nt = 0; nt < 3; ++nt)
            yf[nt] = *reinterpret_cast<const half8*>(&lds[(nt * NT + lr) * YLD + kc * 32 + lk]);
        #pragma unroll
        for (int q = 0; q < 2; ++q)
            #pragma unroll
            for (int nt = 0; nt < 3; ++nt)
                Dacc[q][nt] = __builtin_amdgcn_mfma_f32_16x16x32_f16(af[q], yf[nt], Dacc[q][nt], 0, 0, 0);
    }

    // ---- epilogue: leaky projection (np-exact op order), direct stores ----
    #pragma unroll
    for (int q = 0; q < 2; ++q) {
        const int fbase = (wid * 2 + q) * 16 + (l >> 4) * 4;
        #pragma unroll
        for (int r = 0; r < 4; ++r) {
#pragma clang fp contract(off)
            const float x0 = Yacc[q][0][r], x1 = Yacc[q][1][r], x2 = Yacc[q][2][r];
            const float d0 = Dacc[q][0][r], d1 = Dacc[q][1][r], d2 = Dacc[q][2][r];
            const float dot = (x0*d0 + x1*d1) + x2*d2;
            const float dns = (d0*d0 + d1*d1) + d2*d2;
            const float sc  = dot / (dns + EPSf);
            const bool  pos = (dot >= 0.f);
            const int f = fbase + r;
            const long obase = ((long)(b * Fdim + f) * 3) * Cdim + c0 + lr;
            const float c0v = pos ? x0 : (x0 - sc*d0);
            const float c1v = pos ? x1 : (x1 - sc*d1);
            const float c2v = pos ? x2 : (x2 - sc*d2);
            outp[obase + 0 * Cdim] = 0.2f*x0 + 0.8f*c0v;
            outp[obase + 1 * Cdim] = 0.2f*x1 + 0.8f*c1v;
            outp[obase + 2 * Cdim] = 0.2f*x2 + 0.8f*c2v;
        }
    }
}

// ---------------- fp32 fallback (round-1 kernel, passed) if ws too small ----------------
__device__ __forceinline__ float comp(const float4& v, int k) {
    return k == 0 ? v.x : k == 1 ? v.y : k == 2 ? v.z : v.w;
}

__global__ __launch_bounds__(256)
void fused_cl_lrelu_fp32(const float* __restrict__ Xp, const float* __restrict__ Jp,
                         const float* __restrict__ Ap, const float* __restrict__ Bp,
                         const float* __restrict__ Cp, const float* __restrict__ Wp,
                         float* __restrict__ outp)
{
    __shared__ float4 sabc[4 * Edim * 3];
    __shared__ float  ylds[4 * 3][Fdim];

    const int t   = threadIdx.x;
    const int s0  = blockIdx.x * 4;
    const int b   = s0 / Cdim;
    const int c0  = s0 % Cdim;

    #pragma unroll
    for (int r = 0; r < 4; ++r) {
        const int e  = t;
        const int idx = ((b * Cdim + c0 + r) * Edim + e) * 3;
        float a[3], bb[3], cc[3];
        basis_abc(Xp[idx], Xp[idx+1], Xp[idx+2], Jp[idx], Jp[idx+1], Jp[idx+2], a, bb, cc);
        const int base = (r * Edim + e) * 3;
        sabc[base + 0] = make_float4(a[0], a[1], a[2], bb[0]);
        sabc[base + 1] = make_float4(bb[1], bb[2], cc[0], cc[1]);
        sabc[base + 2] = make_float4(cc[2], 0.f, 0.f, 0.f);
    }
    __syncthreads();

    const int fl = t & 63;
    const int cg = t >> 6;
    float Y[4][3];
    #pragma unroll
    for (int q = 0; q < 4; ++q) Y[q][0] = Y[q][1] = Y[q][2] = 0.f;

    const float4* A4 = reinterpret_cast<const float4*>(Ap);
    const float4* B4 = reinterpret_cast<const float4*>(Bp);
    const float4* C4 = reinterpret_cast<const float4*>(Cp);
    for (int e4 = 0; e4 < Edim / 4; ++e4) {
        float4 wa[4], wb[4], wc[4];
        #pragma unroll
        for (int q = 0; q < 4; ++q) {
            const int f = q * 64 + fl;
            wa[q] = A4[f * (Edim/4) + e4];
            wb[q] = B4[f * (Edim/4) + e4];
            wc[q] = C4[f * (Edim/4) + e4];
        }
        #pragma unroll
        for (int k = 0; k < 4; ++k) {
            const int e = e4 * 4 + k;
            const float4 p0 = sabc[(cg * Edim + e) * 3 + 0];
            const float4 p1 = sabc[(cg * Edim + e) * 3 + 1];
            const float4 p2 = sabc[(cg * Edim + e) * 3 + 2];
            #pragma unroll
            for (int q = 0; q < 4; ++q) {
                const float Af = comp(wa[q], k), Bf = comp(wb[q], k), Cf = comp(wc[q], k);
                Y[q][0] += Af * p0.x + Bf * p0.w + Cf * p1.z;
                Y[q][1] += Af * p0.y + Bf * p1.x + Cf * p1.w;
                Y[q][2] += Af * p0.z + Bf * p1.y + Cf * p2.x;
            }
        }
    }
    #pragma unroll
    for (int q = 0; q < 4; ++q) {
        const int f = q * 64 + fl;
        ylds[cg * 3 + 0][f] = Y[q][0];
        ylds[cg * 3 + 1][f] = Y[q][1];
        ylds[cg * 3 + 2][f] = Y[q][2];
    }
    __syncthreads();

    float D[4][3];
    #pragma unroll
    for (int q = 0; q < 4; ++q) D[q][0] = D[q][1] = D[q][2] = 0.f;
    const float4* W4 = reinterpret_cast<const float4*>(Wp);
    for (int g4 = 0; g4 < Fdim / 4; ++g4) {
        float4 ww[4];
        #pragma unroll
        for (int q = 0; q < 4; ++q) ww[q] = W4[(q * 64 + fl) * (Fdim/4) + g4];
        const float4 y0 = *reinterpret_cast<const float4*>(&ylds[cg * 3 + 0][g4 * 4]);
        const float4 y1 = *reinterpret_cast<const float4*>(&ylds[cg * 3 + 1][g4 * 4]);
        const float4 y2 = *reinterpret_cast<const float4*>(&ylds[cg * 3 + 2][g4 * 4]);
        #pragma unroll
        for (int k = 0; k < 4; ++k) {
            #pragma unroll
            for (int q = 0; q < 4; ++q) {
                const float Wv = comp(ww[q], k);
                D[q][0] += Wv * comp(y0, k);
                D[q][1] += Wv * comp(y1, k);
                D[q][2] += Wv * comp(y2, k);
            }
        }
    }

    float* outl = reinterpret_cast<float*>(sabc);
    #pragma unroll
    for (int q = 0; q < 4; ++q) {
        const int f = q * 64 + fl;
        const float dot = (Y[q][0]*D[q][0] + Y[q][1]*D[q][1]) + Y[q][2]*D[q][2];
        const float dns = (D[q][0]*D[q][0] + D[q][1]*D[q][1]) + D[q][2]*D[q][2];
        const float s   = dot / (dns + EPSf);
        const bool  pos = (dot >= 0.f);
        #pragma unroll
        for (int i = 0; i < 3; ++i) {
            const float x = Y[q][i], d = D[q][i];
            outl[(f * 3 + i) * 4 + cg] = 0.2f*x + 0.8f*(pos ? x : x - s*d);
        }
    }
    __syncthreads();
    const float4* o4 = reinterpret_cast<const float4*>(outl);
    float4* O4 = reinterpret_cast<float4*>(outp);
    const int c4 = c0 >> 2;
    #pragma unroll
    for (int i = 0; i < 3; ++i)
        O4[((b * Fdim + t) * 3 + i) * (Cdim / 4) + c4] = o4[t * 3 + i];
}

extern "C" void kernel_launch(void* const* d_in, const int* in_sizes, int n_in,
                              void* d_out, int out_size, void* d_ws, size_t ws_size,
                              hipStream_t stream) {
    const float* X  = (const float*)d_in[0];
    const float* J  = (const float*)d_in[1];
    const float* A  = (const float*)d_in[2];
    const float* Bw = (const float*)d_in[3];
    const float* Cw = (const float*)d_in[4];
    const float* W  = (const float*)d_in[5];
    float* out = (float*)d_out;

    constexpr size_t WS_NEED = (size_t)(M_ROWS + W_ROWS) * 8 * sizeof(_Float16);  // 512 KiB
    if (ws_size >= WS_NEED) {
        _Float16* wsM = (_Float16*)d_ws;
        _Float16* wsW = wsM + (size_t)M_ROWS * 8;
        prep_weights_f16<<<(M_ROWS + W_ROWS) / 256, 256, 0, stream>>>(A, Bw, Cw, W, wsM);
        fused_mfma_f16<<<Bdim * Cdim / NT, 512, 0, stream>>>(X, J, wsM, wsW, out);
    } else {
        fused_cl_lrelu_fp32<<<Bdim * Cdim / 4, 256, 0, stream>>>(X, J, A, Bw, Cw, W, out);
    }
}